// Round 3
// baseline (241.586 us; speedup 1.0000x reference)
//
#include <hip/hip_runtime.h>

#define Bb 8
#define Cc 256
#define C4 64
#define Nn 4096

typedef short short8 __attribute__((ext_vector_type(8)));
typedef float f32x4 __attribute__((ext_vector_type(4)));
typedef unsigned int u32;

__device__ __forceinline__ unsigned short f2bf(float f) {
  unsigned int u = __float_as_uint(f);
  return (unsigned short)((u + 0x7FFFu + ((u >> 16) & 1u)) >> 16);
}
__device__ __forceinline__ float bf2f(unsigned short h) {
  return __uint_as_float(((unsigned int)h) << 16);
}
__device__ __forceinline__ u32 cvtpk(float lo, float hi) {
  u32 r;
  asm("v_cvt_pk_bf16_f32 %0, %1, %2" : "=v"(r) : "v"(lo), "v"(hi));
  return r;
}
__device__ __forceinline__ f32x4 fz4() {
  f32x4 z; z[0] = 0.f; z[1] = 0.f; z[2] = 0.f; z[3] = 0.f; return z;
}
__device__ __forceinline__ void gll16(const void* g, void* l) {
  __builtin_amdgcn_global_load_lds(
      (const __attribute__((address_space(1))) u32*)g,
      (__attribute__((address_space(3))) u32*)l, 16, 0, 0);
}
#define BAR_LGKM()                                          \
  asm volatile("s_waitcnt lgkmcnt(0)" ::: "memory");        \
  __builtin_amdgcn_s_barrier()
#define BAR_VM_LGKM()                                              \
  asm volatile("s_waitcnt vmcnt(0) lgkmcnt(0)" ::: "memory");      \
  __builtin_amdgcn_s_barrier()

// ---------------- K0: weight prep (bf16 + hi/lo split for w_qk) ----------------
__global__ void k0_weights(const float* __restrict__ wqk, const float* __restrict__ wv,
                           const float* __restrict__ wt,
                           unsigned short* __restrict__ wqk_hi, unsigned short* __restrict__ wqk_lo,
                           unsigned short* __restrict__ wv_bf, unsigned short* __restrict__ wt_bf) {
  int idx = blockIdx.x * 256 + threadIdx.x;
  if (idx < C4 * Cc) {
    float f = wqk[idx];
    unsigned short h = f2bf(f);
    wqk_hi[idx] = h;
    wqk_lo[idx] = f2bf(f - bf2f(h));
  }
  if (idx < Cc * Cc) {
    wv_bf[idx] = f2bf(wv[idx]);
    wt_bf[idx] = f2bf(wt[idx]);
  }
}

// ---------------- K23: qk (split hi/lo) + x_v ----------------
// qk_hi/lo: [b][n][64] bf16   xvb: [b][c][n] bf16
__global__ __launch_bounds__(512) void k23_qkv(
    const float* __restrict__ x,
    const unsigned short* __restrict__ wqk_hi, const unsigned short* __restrict__ wqk_lo,
    const unsigned short* __restrict__ wv_bf, const float* __restrict__ bv,
    unsigned short* __restrict__ qk_hi, unsigned short* __restrict__ qk_lo,
    unsigned short* __restrict__ xvb) {
  __shared__ unsigned short xh[64 * 264];
  __shared__ unsigned short xl[64 * 264];
  const int bid = blockIdx.x;
  const int b = bid & 7, n0 = (bid >> 3) * 64, tid = threadIdx.x;
  {
    const int cc = tid >> 3, nn = (tid & 7) * 8;
    #pragma unroll
    for (int ph = 0; ph < 4; ++ph) {
      int c = cc + ph * 64;
      const float* src = x + ((size_t)(b * Cc + c)) * Nn + n0 + nn;
      float4 v0 = *(const float4*)(src);
      float4 v1 = *(const float4*)(src + 4);
      float vv[8] = {v0.x, v0.y, v0.z, v0.w, v1.x, v1.y, v1.z, v1.w};
      #pragma unroll
      for (int j = 0; j < 8; ++j) {
        unsigned short h = f2bf(vv[j]);
        xh[(nn + j) * 264 + c] = h;
        xl[(nn + j) * 264 + c] = f2bf(vv[j] - bf2f(h));
      }
    }
  }
  __syncthreads();
  const int w = tid >> 6, lane = tid & 63, l15 = lane & 15, l4 = lane >> 4;
  {
    const int fn = w >> 1, ob = (w & 1) * 32;
    f32x4 acc[2] = {fz4(), fz4()};
    #pragma unroll
    for (int kb = 0; kb < 8; ++kb) {
      const int k = kb * 32 + l4 * 8;
      short8 ah = *(const short8*)(xh + (fn * 16 + l15) * 264 + k);
      short8 al = *(const short8*)(xl + (fn * 16 + l15) * 264 + k);
      #pragma unroll
      for (int f = 0; f < 2; ++f) {
        const int o = ob + f * 16 + l15;
        short8 bh = *(const short8*)(wqk_hi + o * Cc + k);
        short8 bl = *(const short8*)(wqk_lo + o * Cc + k);
        acc[f] = __builtin_amdgcn_mfma_f32_16x16x32_bf16(ah, bh, acc[f], 0, 0, 0);
        acc[f] = __builtin_amdgcn_mfma_f32_16x16x32_bf16(ah, bl, acc[f], 0, 0, 0);
        acc[f] = __builtin_amdgcn_mfma_f32_16x16x32_bf16(al, bh, acc[f], 0, 0, 0);
      }
    }
    #pragma unroll
    for (int f = 0; f < 2; ++f) {
      #pragma unroll
      for (int i = 0; i < 4; ++i) {
        const int n = n0 + fn * 16 + l4 * 4 + i;
        const int o = ob + f * 16 + l15;
        float v = acc[f][i];
        unsigned short h = f2bf(v);
        qk_hi[((size_t)b * Nn + n) * C4 + o] = h;
        qk_lo[((size_t)b * Nn + n) * C4 + o] = f2bf(v - bf2f(h));
      }
    }
  }
  {
    const int cb = w * 32;
    f32x4 acc[2][4];
    #pragma unroll
    for (int a = 0; a < 2; ++a)
      #pragma unroll
      for (int q = 0; q < 4; ++q) acc[a][q] = fz4();
    #pragma unroll
    for (int kb = 0; kb < 8; ++kb) {
      const int k = kb * 32 + l4 * 8;
      short8 bfr[4];
      #pragma unroll
      for (int fnb = 0; fnb < 4; ++fnb)
        bfr[fnb] = *(const short8*)(xh + (fnb * 16 + l15) * 264 + k);
      #pragma unroll
      for (int fc = 0; fc < 2; ++fc) {
        const int c = cb + fc * 16 + l15;
        short8 a = *(const short8*)(wv_bf + c * Cc + k);
        #pragma unroll
        for (int fnb = 0; fnb < 4; ++fnb)
          acc[fc][fnb] = __builtin_amdgcn_mfma_f32_16x16x32_bf16(a, bfr[fnb], acc[fc][fnb], 0, 0, 0);
      }
    }
    #pragma unroll
    for (int fc = 0; fc < 2; ++fc)
      #pragma unroll
      for (int fnb = 0; fnb < 4; ++fnb)
        #pragma unroll
        for (int i = 0; i < 4; ++i) {
          const int c = cb + fc * 16 + l4 * 4 + i;
          const int n = n0 + fnb * 16 + l15;
          float v = acc[fc][fnb][i] + bv[c];
          xvb[((size_t)b * Cc + c) * Nn + n] = f2bf(v);
        }
  }
}

// ---------------- K4: softmax row stats ----------------
// Block: 64 n-rows, loop m in 64-chunks. qn in regs; qm double-buffered gll (XOR src).
__global__ __launch_bounds__(512, 4) void k4_stats(
    const unsigned short* __restrict__ qk_hi, const unsigned short* __restrict__ qk_lo,
    float* __restrict__ stats) {
  __shared__ __align__(16) char qsm[32768];  // [buf2][hi/lo][64*64 bf16]
  __shared__ float red[64][4];
  const int bid = blockIdx.x;
  const int b = bid & 7, n0 = (bid >> 3) * 64, tid = threadIdx.x;
  const int w = tid >> 6, lane = tid & 63, l15 = lane & 15, l4 = lane >> 4;
  const int wa = w >> 2, wb = w & 3;
  const int lr = lane >> 3, lc = lane & 7;
  const size_t bq = (size_t)b * Nn;

  short8 qnh_r[2][2], qnl_r[2][2];
  #pragma unroll
  for (int kb = 0; kb < 2; ++kb)
    #pragma unroll
    for (int fn = 0; fn < 2; ++fn) {
      size_t o = (bq + n0 + wa * 32 + fn * 16 + l15) * C4 + kb * 32 + l4 * 8;
      qnh_r[kb][fn] = *(const short8*)(qk_hi + o);
      qnl_r[kb][fn] = *(const short8*)(qk_lo + o);
    }

  const int srcsw = (lc ^ lr) * 8;
  auto stage = [&](int buf, int mt) {
    size_t gro = (bq + (size_t)mt * 64 + w * 8 + lr) * C4 + srcsw;
    gll16(qk_hi + gro, qsm + buf * 16384 + w * 1024);
    gll16(qk_lo + gro, qsm + buf * 16384 + 8192 + w * 1024);
  };
  stage(0, 0);

  float sm[2] = {0.f, 0.f};
  for (int it = 0; it < 64; ++it) {
    BAR_VM_LGKM();
    if (it + 1 < 64) stage((it + 1) & 1, it + 1);
    const char* qb = qsm + (it & 1) * 16384;
    f32x4 g[2] = {fz4(), fz4()};
    #pragma unroll
    for (int kb = 0; kb < 2; ++kb) {
      u32 ad = (u32)((wb * 16 + l15) * 128 + (((kb * 4 + l4) ^ (l15 & 7)) * 16));
      short8 ah = *(const short8*)(qb + ad);
      short8 al = *(const short8*)(qb + 8192 + ad);
      #pragma unroll
      for (int fn = 0; fn < 2; ++fn) {
        g[fn] = __builtin_amdgcn_mfma_f32_16x16x32_bf16(ah, qnh_r[kb][fn], g[fn], 0, 0, 0);
        g[fn] = __builtin_amdgcn_mfma_f32_16x16x32_bf16(ah, qnl_r[kb][fn], g[fn], 0, 0, 0);
        g[fn] = __builtin_amdgcn_mfma_f32_16x16x32_bf16(al, qnh_r[kb][fn], g[fn], 0, 0, 0);
      }
    }
    #pragma unroll
    for (int fn = 0; fn < 2; ++fn)
      #pragma unroll
      for (int i = 0; i < 4; ++i)
        sm[fn] += __expf(g[fn][i] - 64.0f);
  }
  #pragma unroll
  for (int fn = 0; fn < 2; ++fn) {
    sm[fn] += __shfl_xor(sm[fn], 16, 64);
    sm[fn] += __shfl_xor(sm[fn], 32, 64);
  }
  if (l4 == 0) {
    #pragma unroll
    for (int fn = 0; fn < 2; ++fn) red[wa * 32 + fn * 16 + l15][wb] = sm[fn];
  }
  __syncthreads();
  if (tid < 64) {
    float t = red[tid][0] + red[tid][1] + red[tid][2] + red[tid][3];
    stats[bq + n0 + tid] = 64.0f + __logf(t);
  }
}

// ---------------- K5: fused attention-apply + conv_t + BN + ReLU + residual ----------------
// Block: 64 m-cols of x_r, loop n in 64-chunks. MT=64/NT=64, 56KB LDS -> 2 blocks/CU.
__global__ __launch_bounds__(512, 4) void k5_main(
    const float* __restrict__ x,
    const unsigned short* __restrict__ qk_hi, const unsigned short* __restrict__ qk_lo,
    const unsigned short* __restrict__ xvb, const float* __restrict__ stats,
    const unsigned short* __restrict__ wt_bf, const float* __restrict__ bt,
    const float* __restrict__ gamma, const float* __restrict__ beta,
    const float* __restrict__ rmean, const float* __restrict__ rvar,
    float* __restrict__ out) {
  __shared__ __align__(16) char smem[57344];
  // [0,8192)=qn_hi [64][64]; [8192,16384)=qn_lo; [16384,24576)=PT [64m][64n]; [24576,57344)=xv [256][64]
  char* PTb = smem + 16384;
  char* xvLb = smem + 24576;
  const int bid = blockIdx.x;
  const int b = bid & 7, m0 = (bid >> 3) * 64, tid = threadIdx.x;
  const int w = tid >> 6, lane = tid & 63, l15 = lane & 15, l4 = lane >> 4;
  const int wa = w >> 2, wb = w & 3;
  const int lr = lane >> 3, lc = lane & 7;
  const size_t bq = (size_t)b * Nn;
  const unsigned short* xvbb = xvb + (size_t)b * Cc * Nn;
  const int srcsw = (lc ^ lr) * 8;
  const int swz15 = (l15 & 7) << 4;

  // stationary qm fragments (B operand rows m = m0 + wb*16 + l15)
  short8 qmh_r[2], qml_r[2];
  #pragma unroll
  for (int kb = 0; kb < 2; ++kb) {
    size_t o = (bq + m0 + wb * 16 + l15) * C4 + kb * 32 + l4 * 8;
    qmh_r[kb] = *(const short8*)(qk_hi + o);
    qml_r[kb] = *(const short8*)(qk_lo + o);
  }
  f32x4 acc[2][4];
  #pragma unroll
  for (int a = 0; a < 2; ++a)
    #pragma unroll
    for (int q = 0; q < 4; ++q) acc[a][q] = fz4();
  asm volatile("s_waitcnt vmcnt(0)" ::: "memory");  // qm_r landed: vmcnt clean before loop

  for (int it = 0; it < 64; ++it) {
    BAR_LGKM();  // A: previous iteration's LDS reads complete
    {  // qn gll (2): rows n = it*64 + w*8 + lr, linear dest, XOR-swizzled source
      size_t gro = (bq + (size_t)it * 64 + w * 8 + lr) * C4 + srcsw;
      gll16(qk_hi + gro, smem + w * 1024);
      gll16(qk_lo + gro, smem + 8192 + w * 1024);
    }
    #pragma unroll
    for (int j = 0; j < 4; ++j) {  // xv gll (4)
      int q = w * 4 + j;
      int c = q * 8 + lr;
      gll16(xvbb + (size_t)c * Nn + it * 64 + srcsw, xvLb + q * 1024);
    }
    asm volatile("s_waitcnt vmcnt(4)" ::: "memory");  // qn landed; xv (4) still in flight
    __builtin_amdgcn_s_barrier();  // B

    // G = qn x qm (3-term split): D rows = n (l4*4+i), cols = m (l15)
    f32x4 g[2] = {fz4(), fz4()};
    #pragma unroll
    for (int kb = 0; kb < 2; ++kb)
      #pragma unroll
      for (int fn = 0; fn < 2; ++fn) {
        u32 ad = (u32)((wa * 32 + fn * 16 + l15) * 128 + (((kb * 4 + l4) ^ (l15 & 7)) * 16));
        short8 ah = *(const short8*)(smem + ad);
        short8 al = *(const short8*)(smem + 8192 + ad);
        g[fn] = __builtin_amdgcn_mfma_f32_16x16x32_bf16(ah, qmh_r[kb], g[fn], 0, 0, 0);
        g[fn] = __builtin_amdgcn_mfma_f32_16x16x32_bf16(ah, qml_r[kb], g[fn], 0, 0, 0);
        g[fn] = __builtin_amdgcn_mfma_f32_16x16x32_bf16(al, qmh_r[kb], g[fn], 0, 0, 0);
      }
    // P = exp(G - a_n), packed bf16, swizzled PT write
    #pragma unroll
    for (int fn = 0; fn < 2; ++fn) {
      float4 an = *(const float4*)(stats + bq + it * 64 + wa * 32 + fn * 16 + l4 * 4);
      uint2 pk;
      pk.x = cvtpk(__expf(g[fn][0] - an.x), __expf(g[fn][1] - an.y));
      pk.y = cvtpk(__expf(g[fn][2] - an.z), __expf(g[fn][3] - an.w));
      int m = wb * 16 + l15;
      *(uint2*)(PTb + m * 128 + ((wa * 64 + fn * 32 + l4 * 8) ^ swz15)) = pk;
    }
    BAR_VM_LGKM();  // C: xv landed + PT visible

    // PV: x_r^T[m][c] += P[m][n] * xv[c][n]
    #pragma unroll
    for (int kb = 0; kb < 2; ++kb) {
      short8 pa[2], xb[4];
      #pragma unroll
      for (int fm = 0; fm < 2; ++fm)
        pa[fm] = *(const short8*)(PTb + (wa * 32 + fm * 16 + l15) * 128 +
                                  ((kb * 64 + l4 * 16) ^ swz15));
      #pragma unroll
      for (int fc = 0; fc < 4; ++fc) {
        int c = wb * 64 + fc * 16 + l15;
        xb[fc] = *(const short8*)(xvLb + c * 128 + (((kb * 4 + l4) ^ (l15 & 7)) * 16));
      }
      #pragma unroll
      for (int fm = 0; fm < 2; ++fm)
        #pragma unroll
        for (int fc = 0; fc < 4; ++fc)
          acc[fm][fc] = __builtin_amdgcn_mfma_f32_16x16x32_bf16(pa[fm], xb[fc], acc[fm][fc], 0, 0, 0);
    }
  }
  BAR_LGKM();

  // Epilogue: s^T = x - x_r^T into st[64][264], then t = w_t.s + b_t, BN, ReLU, +x
  unsigned short* st = (unsigned short*)smem;  // [64][264] bf16, reuses main-loop LDS
  #pragma unroll
  for (int fm = 0; fm < 2; ++fm)
    #pragma unroll
    for (int fc = 0; fc < 4; ++fc) {
      int c = wb * 64 + fc * 16 + l15;
      const float* xp = x + ((size_t)b * Cc + c) * Nn + m0 + wa * 32 + fm * 16 + l4 * 4;
      #pragma unroll
      for (int i = 0; i < 4; ++i) {
        int m = wa * 32 + fm * 16 + l4 * 4 + i;
        st[m * 264 + c] = f2bf(xp[i] - acc[fm][fc][i]);
      }
    }
  __syncthreads();
  {
    const int ob = (w >> 1) * 64, mb2 = (w & 1) * 32;
    f32x4 t[4][2];
    #pragma unroll
    for (int a = 0; a < 4; ++a)
      #pragma unroll
      for (int q = 0; q < 2; ++q) t[a][q] = fz4();
    #pragma unroll
    for (int kb = 0; kb < 8; ++kb) {
      const int k = kb * 32 + l4 * 8;
      short8 bfr[2];
      #pragma unroll
      for (int fm2 = 0; fm2 < 2; ++fm2)
        bfr[fm2] = *(const short8*)(st + (mb2 + fm2 * 16 + l15) * 264 + k);
      #pragma unroll
      for (int fo = 0; fo < 4; ++fo) {
        short8 a = *(const short8*)(wt_bf + (ob + fo * 16 + l15) * Cc + k);
        #pragma unroll
        for (int fm2 = 0; fm2 < 2; ++fm2)
          t[fo][fm2] = __builtin_amdgcn_mfma_f32_16x16x32_bf16(a, bfr[fm2], t[fo][fm2], 0, 0, 0);
      }
    }
    #pragma unroll
    for (int fo = 0; fo < 4; ++fo)
      #pragma unroll
      for (int i = 0; i < 4; ++i) {
        const int o = ob + fo * 16 + l4 * 4 + i;
        const float inv = gamma[o] * rsqrtf(rvar[o] + 1e-5f);
        const float addv = beta[o] - rmean[o] * inv;
        const float btv = bt[o];
        #pragma unroll
        for (int fm2 = 0; fm2 < 2; ++fm2) {
          const int m = m0 + mb2 + fm2 * 16 + l15;
          float tv = t[fo][fm2][i] + btv;
          float bn = tv * inv + addv;
          float xr = x[((size_t)b * Cc + o) * Nn + m];
          out[((size_t)b * Cc + o) * Nn + m] = xr + fmaxf(bn, 0.0f);
        }
      }
  }
}

extern "C" void kernel_launch(void* const* d_in, const int* in_sizes, int n_in,
                              void* d_out, int out_size, void* d_ws, size_t ws_size,
                              hipStream_t stream) {
  const float* x = (const float*)d_in[0];
  const float* wqk = (const float*)d_in[1];
  const float* wv = (const float*)d_in[2];
  const float* bv = (const float*)d_in[3];
  const float* wt = (const float*)d_in[4];
  const float* bt = (const float*)d_in[5];
  const float* gamma = (const float*)d_in[6];
  const float* beta = (const float*)d_in[7];
  const float* rmean = (const float*)d_in[8];
  const float* rvar = (const float*)d_in[9];
  float* out = (float*)d_out;

  char* ws = (char*)d_ws;
  size_t off = 0;
  auto alloc = [&](size_t nb) {
    char* p = ws + off;
    off += (nb + 255) & ~(size_t)255;
    return p;
  };
  unsigned short* qk_hi = (unsigned short*)alloc((size_t)Bb * Nn * C4 * 2);
  unsigned short* qk_lo = (unsigned short*)alloc((size_t)Bb * Nn * C4 * 2);
  unsigned short* xvb = (unsigned short*)alloc((size_t)Bb * Cc * Nn * 2);
  float* stats = (float*)alloc((size_t)Bb * Nn * 4);
  unsigned short* wqk_hi = (unsigned short*)alloc((size_t)C4 * Cc * 2);
  unsigned short* wqk_lo = (unsigned short*)alloc((size_t)C4 * Cc * 2);
  unsigned short* wv_bf = (unsigned short*)alloc((size_t)Cc * Cc * 2);
  unsigned short* wt_bf = (unsigned short*)alloc((size_t)Cc * Cc * 2);

  k0_weights<<<dim3(256), dim3(256), 0, stream>>>(wqk, wv, wt, wqk_hi, wqk_lo, wv_bf, wt_bf);
  k23_qkv<<<dim3(512), dim3(512), 0, stream>>>(x, wqk_hi, wqk_lo, wv_bf, bv, qk_hi, qk_lo, xvb);
  k4_stats<<<dim3(512), dim3(512), 0, stream>>>(qk_hi, qk_lo, stats);
  k5_main<<<dim3(512), dim3(512), 0, stream>>>(x, qk_hi, qk_lo, xvb, stats, wt_bf, bt,
                                               gamma, beta, rmean, rvar, out);
}

// Round 5
// 190.635 us; speedup vs baseline: 1.2673x; 1.2673x over previous
//
#include <hip/hip_runtime.h>

#define Bb 8
#define Cc 256
#define C4 64
#define Nn 4096

typedef _Float16 half8 __attribute__((ext_vector_type(8)));
typedef float f32x4 __attribute__((ext_vector_type(4)));
typedef unsigned int u32;

__device__ __forceinline__ f32x4 fz4() {
  f32x4 z; z[0] = 0.f; z[1] = 0.f; z[2] = 0.f; z[3] = 0.f; return z;
}
__device__ __forceinline__ f32x4 mfma16(half8 a, half8 b, f32x4 c) {
  return __builtin_amdgcn_mfma_f32_16x16x32_f16(a, b, c, 0, 0, 0);
}
__device__ __forceinline__ u32 pkrtz(float a, float b) {
  typedef __fp16 h2n __attribute__((ext_vector_type(2)));
  h2n h = __builtin_amdgcn_cvt_pkrtz(a, b);
  return __builtin_bit_cast(u32, h);
}
__device__ __forceinline__ void gll16(const void* g, void* l) {
  __builtin_amdgcn_global_load_lds(
      (const __attribute__((address_space(1))) u32*)g,
      (__attribute__((address_space(3))) u32*)l, 16, 0, 0);
}
#define BAR_LGKM()                                          \
  asm volatile("s_waitcnt lgkmcnt(0)" ::: "memory");        \
  __builtin_amdgcn_s_barrier()
#define BAR_VM_LGKM()                                              \
  asm volatile("s_waitcnt vmcnt(0) lgkmcnt(0)" ::: "memory");      \
  __builtin_amdgcn_s_barrier()

// ---------------- K0: weight prep (f16; hi/lo split only for w_qk) ----------------
__global__ void k0_weights(const float* __restrict__ wqk, const float* __restrict__ wv,
                           const float* __restrict__ wt,
                           _Float16* __restrict__ wqkh, _Float16* __restrict__ wqkl,
                           _Float16* __restrict__ wvf, _Float16* __restrict__ wtf) {
  int idx = blockIdx.x * 256 + threadIdx.x;
  if (idx < C4 * Cc) {
    float f = wqk[idx];
    _Float16 h = (_Float16)f;
    wqkh[idx] = h;
    wqkl[idx] = (_Float16)(f - (float)h);
  }
  if (idx < Cc * Cc) {
    wvf[idx] = (_Float16)wv[idx];
    wtf[idx] = (_Float16)wt[idx];
  }
}

// ---------------- K23: qk (f16, computed with hi/lo split) + x_v ----------------
// qkf: [b][n][64] f16   xvf: [b][c][n] f16
__global__ __launch_bounds__(512) void k23_qkv(
    const float* __restrict__ x,
    const _Float16* __restrict__ wqkh, const _Float16* __restrict__ wqkl,
    const _Float16* __restrict__ wvf, const float* __restrict__ bv,
    _Float16* __restrict__ qkf, _Float16* __restrict__ xvf) {
  __shared__ _Float16 xh[64 * 264];  // [n][c] transposed x, hi
  __shared__ _Float16 xl[64 * 264];  // lo
  const int bid = blockIdx.x;
  const int b = bid & 7, n0 = (bid >> 3) * 64, tid = threadIdx.x;
  {
    const int cc = tid >> 3, nn = (tid & 7) * 8;
    #pragma unroll
    for (int ph = 0; ph < 4; ++ph) {
      int c = cc + ph * 64;
      const float* src = x + ((size_t)(b * Cc + c)) * Nn + n0 + nn;
      float4 v0 = *(const float4*)(src);
      float4 v1 = *(const float4*)(src + 4);
      float vv[8] = {v0.x, v0.y, v0.z, v0.w, v1.x, v1.y, v1.z, v1.w};
      #pragma unroll
      for (int j = 0; j < 8; ++j) {
        _Float16 h = (_Float16)vv[j];
        xh[(nn + j) * 264 + c] = h;
        xl[(nn + j) * 264 + c] = (_Float16)(vv[j] - (float)h);
      }
    }
  }
  __syncthreads();
  const int w = tid >> 6, lane = tid & 63, l15 = lane & 15, l4 = lane >> 4;
  // ---- q: out [64 n][64 o], K=256, 3-term f16 split ----
  {
    const int fn = w >> 1, ob = (w & 1) * 32;
    f32x4 acc[2] = {fz4(), fz4()};
    #pragma unroll
    for (int kb = 0; kb < 8; ++kb) {
      const int k = kb * 32 + l4 * 8;
      half8 ah = *(const half8*)(xh + (fn * 16 + l15) * 264 + k);
      half8 al = *(const half8*)(xl + (fn * 16 + l15) * 264 + k);
      #pragma unroll
      for (int f = 0; f < 2; ++f) {
        const int o = ob + f * 16 + l15;
        half8 bh = *(const half8*)(wqkh + o * Cc + k);
        half8 bl = *(const half8*)(wqkl + o * Cc + k);
        acc[f] = mfma16(ah, bh, acc[f]);
        acc[f] = mfma16(ah, bl, acc[f]);
        acc[f] = mfma16(al, bh, acc[f]);
      }
    }
    #pragma unroll
    for (int f = 0; f < 2; ++f)
      #pragma unroll
      for (int i = 0; i < 4; ++i) {
        const int n = n0 + fn * 16 + l4 * 4 + i;
        const int o = ob + f * 16 + l15;
        qkf[((size_t)b * Nn + n) * C4 + o] = (_Float16)acc[f][i];
      }
  }
  // ---- x_v: out [256 c][64 n], K=256, single f16 ----
  {
    const int cb = w * 32;
    f32x4 acc[2][4];
    #pragma unroll
    for (int a = 0; a < 2; ++a)
      #pragma unroll
      for (int q = 0; q < 4; ++q) acc[a][q] = fz4();
    #pragma unroll
    for (int kb = 0; kb < 8; ++kb) {
      const int k = kb * 32 + l4 * 8;
      half8 bfr[4];
      #pragma unroll
      for (int fnb = 0; fnb < 4; ++fnb)
        bfr[fnb] = *(const half8*)(xh + (fnb * 16 + l15) * 264 + k);
      #pragma unroll
      for (int fc = 0; fc < 2; ++fc) {
        const int c = cb + fc * 16 + l15;
        half8 a = *(const half8*)(wvf + c * Cc + k);
        #pragma unroll
        for (int fnb = 0; fnb < 4; ++fnb)
          acc[fc][fnb] = mfma16(a, bfr[fnb], acc[fc][fnb]);
      }
    }
    #pragma unroll
    for (int fc = 0; fc < 2; ++fc)
      #pragma unroll
      for (int fnb = 0; fnb < 4; ++fnb)
        #pragma unroll
        for (int i = 0; i < 4; ++i) {
          const int c = cb + fc * 16 + l4 * 4 + i;
          const int n = n0 + fnb * 16 + l15;
          xvf[((size_t)b * Cc + c) * Nn + n] = (_Float16)(acc[fc][fnb][i] + bv[c]);
        }
  }
}

// ---------------- K4: softmax row stats  a_n = 64 + log(sum_m exp(E-64)) ----------------
// Block: 64 n (in regs), loop m in 128-chunks, qm dbuf via gll (XOR-swizzled source).
__global__ __launch_bounds__(512, 4) void k4_stats(
    const _Float16* __restrict__ qkf, float* __restrict__ stats) {
  __shared__ __align__(16) char qsm[2][16384];  // [buf][128 m][64 k] f16, swizzled
  __shared__ float red[64][4];
  const int bid = blockIdx.x;
  const int b = bid & 7, n0 = (bid >> 3) * 64, tid = threadIdx.x;
  const int w = tid >> 6, lane = tid & 63, l15 = lane & 15, l4 = lane >> 4;
  const int wa = w >> 2, wb = w & 3;
  const int lr = lane >> 3, lc = lane & 7;
  const size_t bq = (size_t)b * Nn;

  half8 qn_r[2][2];
  #pragma unroll
  for (int kb = 0; kb < 2; ++kb)
    #pragma unroll
    for (int fn = 0; fn < 2; ++fn)
      qn_r[kb][fn] = *(const half8*)(qkf + (bq + n0 + wa * 32 + fn * 16 + l15) * C4 +
                                     kb * 32 + l4 * 8);

  auto stage = [&](int buf, int mt) {
    size_t gro = (bq + (size_t)mt * 128 + (tid >> 3)) * C4 + (lc ^ lr) * 8;
    gll16(qkf + gro, qsm[buf] + w * 1024);
    gll16(qkf + gro + (size_t)64 * C4, qsm[buf] + 8192 + w * 1024);
  };
  stage(0, 0);

  float sm[2] = {0.f, 0.f};
  for (int it = 0; it < 32; ++it) {
    BAR_VM_LGKM();
    if (it + 1 < 32) stage((it + 1) & 1, it + 1);
    const char* qb = qsm[it & 1];
    f32x4 g[2][2];
    #pragma unroll
    for (int fa = 0; fa < 2; ++fa)
      #pragma unroll
      for (int fn = 0; fn < 2; ++fn) g[fa][fn] = fz4();
    #pragma unroll
    for (int fa = 0; fa < 2; ++fa)
      #pragma unroll
      for (int kb = 0; kb < 2; ++kb) {
        const int m = fa * 64 + wb * 16 + l15;
        u32 ad = (u32)(m * 128 + (((kb * 4 + l4) ^ (l15 & 7)) * 16));
        half8 ah = *(const half8*)(qb + ad);
        #pragma unroll
        for (int fn = 0; fn < 2; ++fn)
          g[fa][fn] = mfma16(ah, qn_r[kb][fn], g[fa][fn]);
      }
    #pragma unroll
    for (int fa = 0; fa < 2; ++fa)
      #pragma unroll
      for (int fn = 0; fn < 2; ++fn)
        #pragma unroll
        for (int i = 0; i < 4; ++i)
          sm[fn] += __expf(g[fa][fn][i] - 64.0f);
  }
  #pragma unroll
  for (int fn = 0; fn < 2; ++fn) {
    sm[fn] += __shfl_xor(sm[fn], 16, 64);
    sm[fn] += __shfl_xor(sm[fn], 32, 64);
  }
  if (l4 == 0) {
    #pragma unroll
    for (int fn = 0; fn < 2; ++fn) red[wa * 32 + fn * 16 + l15][wb] = sm[fn];
  }
  __syncthreads();
  if (tid < 64) {
    float t = red[tid][0] + red[tid][1] + red[tid][2] + red[tid][3];
    stats[bq + n0 + tid] = 64.0f + __logf(t);
  }
}

// ---------------- K5: fused attention-apply + conv_t + BN + ReLU + residual ----------------
// 2-barrier pipeline: qn single-buf (issued post-C), xv double-buf (issued 1 iter early).
__global__ __launch_bounds__(512, 4) void k5_main(
    const float* __restrict__ x,
    const _Float16* __restrict__ qkf, const _Float16* __restrict__ xvf,
    const float* __restrict__ stats,
    const _Float16* __restrict__ wtf, const float* __restrict__ bt,
    const float* __restrict__ gamma, const float* __restrict__ beta,
    const float* __restrict__ rmean, const float* __restrict__ rvar,
    float* __restrict__ out) {
  __shared__ __align__(16) char smem[81920];
  // [0,8K) qn [64n][64k] f16 swz | [8K,16K) PT [64m][64n] f16 swz | [16K,48K) xvA | [48K,80K) xvB
  const int bid = blockIdx.x;
  const int b = bid & 7, m0 = (bid >> 3) * 64, tid = threadIdx.x;
  const int w = tid >> 6, lane = tid & 63, l15 = lane & 15, l4 = lane >> 4;
  const int wa = w >> 2;  // m 32-block (G-B & PV-A rows)
  const int wb = w & 3;   // G: n 16-block; PV: c 64-block
  const int lr = lane >> 3, lc = lane & 7;
  const size_t bq = (size_t)b * Nn;
  const _Float16* xvbb = xvf + (size_t)b * Cc * Nn;
  const int key = l15 & 7;

  // stationary qm fragments (rows m = m0 + wa*32 + fm*16 + l15)
  half8 qm_r[2][2];
  #pragma unroll
  for (int kb = 0; kb < 2; ++kb)
    #pragma unroll
    for (int fm = 0; fm < 2; ++fm)
      qm_r[kb][fm] = *(const half8*)(qkf + (bq + m0 + wa * 32 + fm * 16 + l15) * C4 +
                                     kb * 32 + l4 * 8);

  auto stage_qn = [&](int itx) {
    gll16(qkf + (bq + (size_t)itx * 64 + (tid >> 3)) * C4 + (lc ^ lr) * 8, smem + w * 1024);
  };
  auto stage_xv = [&](int itx, int bufn) {
    #pragma unroll
    for (int j = 0; j < 4; ++j) {
      int c = j * 64 + w * 8 + lr;
      gll16(xvbb + (size_t)c * Nn + itx * 64 + (lc ^ lr) * 8,
            smem + 16384 + bufn * 32768 + j * 8192 + w * 1024);
    }
  };

  f32x4 acc[2][4];
  #pragma unroll
  for (int a = 0; a < 2; ++a)
    #pragma unroll
    for (int q = 0; q < 4; ++q) acc[a][q] = fz4();

  stage_qn(0);
  stage_xv(0, 0);

  for (int it = 0; it < 64; ++it) {
    const int cur = it & 1;
    BAR_VM_LGKM();  // B: qn[it] + xv[it] landed; prev PV reads complete
    if (it + 1 < 64) stage_xv(it + 1, cur ^ 1);  // hides under G + PV
    // G = qn x qm : D rows = n (wb*16 + l4*4+i), cols = m (wa*32 + fm*16 + l15)
    f32x4 g[2] = {fz4(), fz4()};
    #pragma unroll
    for (int kb = 0; kb < 2; ++kb) {
      half8 ah = *(const half8*)(smem + (wb * 16 + l15) * 128 + ((kb * 4 + l4) ^ key) * 16);
      #pragma unroll
      for (int fm = 0; fm < 2; ++fm)
        g[fm] = mfma16(ah, qm_r[kb][fm], g[fm]);
    }
    // P = exp(G - a_n) -> PT[m][n] f16 swizzled (8B packed writes)
    {
      float4 an = *(const float4*)(stats + bq + (size_t)it * 64 + wb * 16 + l4 * 4);
      #pragma unroll
      for (int fm = 0; fm < 2; ++fm) {
        const int m = wa * 32 + fm * 16 + l15;
        uint2 pk;
        pk.x = pkrtz(__expf(g[fm][0] - an.x), __expf(g[fm][1] - an.y));
        pk.y = pkrtz(__expf(g[fm][2] - an.z), __expf(g[fm][3] - an.w));
        *(uint2*)(smem + 8192 + m * 128 + ((wb * 32 + l4 * 8) ^ (key << 4))) = pk;
      }
    }
    BAR_LGKM();  // C: PT visible; all G-reads of qn done
    if (it + 1 < 64) stage_qn(it + 1);  // hides under PV
    // PV: x_r^T[m][c] += P[m][n] * xv[c][n]
    __builtin_amdgcn_s_setprio(1);
    #pragma unroll
    for (int kb = 0; kb < 2; ++kb) {
      half8 pa[2], xb[4];
      #pragma unroll
      for (int fm = 0; fm < 2; ++fm) {
        const int m = wa * 32 + fm * 16 + l15;
        pa[fm] = *(const half8*)(smem + 8192 + m * 128 + (((kb * 4 + l4) ^ key) * 16));
      }
      #pragma unroll
      for (int fc = 0; fc < 4; ++fc) {
        const int c = wb * 64 + fc * 16 + l15;
        xb[fc] = *(const half8*)(smem + 16384 + cur * 32768 + c * 128 +
                                 (((kb * 4 + l4) ^ key) * 16));
      }
      #pragma unroll
      for (int fm = 0; fm < 2; ++fm)
        #pragma unroll
        for (int fc = 0; fc < 4; ++fc)
          acc[fm][fc] = mfma16(pa[fm], xb[fc], acc[fm][fc]);
    }
    __builtin_amdgcn_s_setprio(0);
  }
  BAR_LGKM();

  // Epilogue: s^T = x - x_r^T into st[64][264] f16, then t = w_t.s + b_t, BN, ReLU, +x
  _Float16* st = (_Float16*)smem;
  #pragma unroll
  for (int fm = 0; fm < 2; ++fm)
    #pragma unroll
    for (int fc = 0; fc < 4; ++fc) {
      int c = wb * 64 + fc * 16 + l15;
      const float* xp = x + ((size_t)b * Cc + c) * Nn + m0 + wa * 32 + fm * 16 + l4 * 4;
      float4 v = *(const float4*)xp;
      float vv[4] = {v.x, v.y, v.z, v.w};
      #pragma unroll
      for (int i = 0; i < 4; ++i) {
        int m = wa * 32 + fm * 16 + l4 * 4 + i;
        st[m * 264 + c] = (_Float16)(vv[i] - acc[fm][fc][i]);
      }
    }
  __syncthreads();
  {
    const int ob = (w >> 1) * 64, mb2 = (w & 1) * 32;
    f32x4 t[4][2];
    #pragma unroll
    for (int a = 0; a < 4; ++a)
      #pragma unroll
      for (int q = 0; q < 2; ++q) t[a][q] = fz4();
    #pragma unroll
    for (int kb = 0; kb < 8; ++kb) {
      const int k = kb * 32 + l4 * 8;
      half8 bfr[2];
      #pragma unroll
      for (int fm2 = 0; fm2 < 2; ++fm2)
        bfr[fm2] = *(const half8*)(st + (mb2 + fm2 * 16 + l15) * 264 + k);
      #pragma unroll
      for (int fo = 0; fo < 4; ++fo) {
        half8 a = *(const half8*)(wtf + (ob + fo * 16 + l15) * Cc + k);
        #pragma unroll
        for (int fm2 = 0; fm2 < 2; ++fm2)
          t[fo][fm2] = mfma16(a, bfr[fm2], t[fo][fm2]);
      }
    }
    #pragma unroll
    for (int fo = 0; fo < 4; ++fo)
      #pragma unroll
      for (int i = 0; i < 4; ++i) {
        const int o = ob + fo * 16 + l4 * 4 + i;
        const float inv = gamma[o] * rsqrtf(rvar[o] + 1e-5f);
        const float addv = beta[o] - rmean[o] * inv;
        const float btv = bt[o];
        #pragma unroll
        for (int fm2 = 0; fm2 < 2; ++fm2) {
          const int m = m0 + mb2 + fm2 * 16 + l15;
          float tv = t[fo][fm2][i] + btv;
          float bn = tv * inv + addv;
          float xr = x[((size_t)b * Cc + o) * Nn + m];
          out[((size_t)b * Cc + o) * Nn + m] = xr + fmaxf(bn, 0.0f);
        }
      }
  }
}

extern "C" void kernel_launch(void* const* d_in, const int* in_sizes, int n_in,
                              void* d_out, int out_size, void* d_ws, size_t ws_size,
                              hipStream_t stream) {
  const float* x = (const float*)d_in[0];
  const float* wqk = (const float*)d_in[1];
  const float* wv = (const float*)d_in[2];
  const float* bv = (const float*)d_in[3];
  const float* wt = (const float*)d_in[4];
  const float* bt = (const float*)d_in[5];
  const float* gamma = (const float*)d_in[6];
  const float* beta = (const float*)d_in[7];
  const float* rmean = (const float*)d_in[8];
  const float* rvar = (const float*)d_in[9];
  float* out = (float*)d_out;

  char* ws = (char*)d_ws;
  size_t off = 0;
  auto alloc = [&](size_t nb) {
    char* p = ws + off;
    off += (nb + 255) & ~(size_t)255;
    return p;
  };
  _Float16* qkf = (_Float16*)alloc((size_t)Bb * Nn * C4 * 2);
  _Float16* xvf = (_Float16*)alloc((size_t)Bb * Cc * Nn * 2);
  float* stats = (float*)alloc((size_t)Bb * Nn * 4);
  _Float16* wqkh = (_Float16*)alloc((size_t)C4 * Cc * 2);
  _Float16* wqkl = (_Float16*)alloc((size_t)C4 * Cc * 2);
  _Float16* wvf = (_Float16*)alloc((size_t)Cc * Cc * 2);
  _Float16* wtf = (_Float16*)alloc((size_t)Cc * Cc * 2);

  k0_weights<<<dim3(256), dim3(256), 0, stream>>>(wqk, wv, wt, wqkh, wqkl, wvf, wtf);
  k23_qkv<<<dim3(512), dim3(512), 0, stream>>>(x, wqkh, wqkl, wvf, bv, qkf, xvf);
  k4_stats<<<dim3(512), dim3(512), 0, stream>>>(qkf, stats);
  k5_main<<<dim3(512), dim3(512), 0, stream>>>(x, qkf, xvf, stats, wtf, bt,
                                               gamma, beta, rmean, rvar, out);
}